// Round 1
// baseline (3775.869 us; speedup 1.0000x reference)
//
#include <hip/hip_runtime.h>
#include <math.h>

#define BB 32
#define TT 2048
#define HH 128

// ---------------------------------------------------------------------------
// proj kernel: out[r, :] = src_row(r) @ W + bias
//   GATHER=true : src_row(r) = emb[tokens[r]]   (embedding lookup)
//   GATHER=false: src_row(r) = src[r]
// Block: 256 threads, 64 rows per block. Grid: (B*T)/64 = 1024 blocks.
// Thread (jj = tid&31, rr = tid>>5): cols 4*jj..4*jj+3, rows rr*8..rr*8+7.
// W rows are read from global (L2-resident, 512 B per wave per k, fully
// shared across lanes); input rows staged in LDS (broadcast reads).
// ---------------------------------------------------------------------------
template <bool GATHER>
__global__ __launch_bounds__(256) void proj_kernel(
    const float* __restrict__ src, const int* __restrict__ tokens,
    const float* __restrict__ W, const float* __restrict__ bias,
    float* __restrict__ out) {
  const int tid = threadIdx.x;
  const int jj = tid & 31;
  const int rr = tid >> 5;
  const int base = blockIdx.x * 64;

  __shared__ __align__(16) float srow[64][HH];
  __shared__ int stok[64];

  if (GATHER) {
    if (tid < 64) stok[tid] = tokens[base + tid];
    __syncthreads();
  }

  // Stage 64 input rows (64*128 floats = 2048 float4) cooperatively.
#pragma unroll
  for (int i = 0; i < 8; ++i) {
    int idx = tid + i * 256;   // float4 index, 32 per row
    int row = idx >> 5;
    int c4 = idx & 31;
    const float* s = GATHER ? (src + (size_t)stok[row] * HH)
                            : (src + (size_t)(base + row) * HH);
    *(float4*)&srow[row][c4 * 4] = *(const float4*)&s[c4 * 4];
  }
  __syncthreads();

  float4 b4 = *(const float4*)&bias[jj * 4];
  float4 acc[8];
#pragma unroll
  for (int i = 0; i < 8; ++i) acc[i] = b4;

  for (int k = 0; k < HH; ++k) {
    float4 w4 = *(const float4*)&W[k * HH + jj * 4];
#pragma unroll
    for (int i = 0; i < 8; ++i) {
      float e = srow[rr * 8 + i][k];
      acc[i].x += e * w4.x;
      acc[i].y += e * w4.y;
      acc[i].z += e * w4.z;
      acc[i].w += e * w4.w;
    }
  }

#pragma unroll
  for (int i = 0; i < 8; ++i) {
    int row = base + rr * 8 + i;
    *(float4*)&out[(size_t)row * HH + jj * 4] = acc[i];
  }
}

// ---------------------------------------------------------------------------
// rnn kernel: in-place recurrence over one layer.
//   io[b,t,:] holds xproj on entry, ys on exit.
//   h_t = mask ? tanh(xp_t + h_{t-1} @ Wh) : h_{t-1}
// One block per batch (128 threads, 2 waves). Wh column j lives in 128 VGPRs
// of thread j. h broadcast via double-buffered LDS -> ONE barrier per step.
// Distance-2 prefetch of xp/token (in-place safe: reads [t+2], writes [t]).
// ---------------------------------------------------------------------------
__global__ __launch_bounds__(128) void rnn_kernel(
    float* io, const float* __restrict__ Wh, const int* __restrict__ tokens) {
  const int b = blockIdx.x;
  const int j = threadIdx.x;

  float w[HH];
#pragma unroll
  for (int k = 0; k < HH; ++k) w[k] = Wh[k * HH + j];  // column j of Wh

  __shared__ __align__(16) float hs[2][HH];
  hs[0][j] = 0.0f;

  float* xp = io + (size_t)b * TT * HH;
  const int* tok = tokens + b * TT;

  float h = 0.0f;
  float xn1 = xp[j];
  int mn1 = tok[0];
  float xn2 = xp[HH + j];
  int mn2 = tok[1];
  __syncthreads();

  for (int t = 0; t < TT; ++t) {
    float x = xn1;
    int m = mn1;
    xn1 = xn2;
    mn1 = mn2;
    if (t + 2 < TT) {
      xn2 = xp[(size_t)(t + 2) * HH + j];
      mn2 = tok[t + 2];
    }

    const float* hb = hs[t & 1];
    float a0 = x, a1 = 0.0f, a2 = 0.0f, a3 = 0.0f;
#pragma unroll
    for (int k = 0; k < HH; k += 4) {
      float4 hv = *(const float4*)&hb[k];
      a0 += hv.x * w[k];
      a1 += hv.y * w[k + 1];
      a2 += hv.z * w[k + 2];
      a3 += hv.w * w[k + 3];
    }
    float acc = (a0 + a1) + (a2 + a3);

    // tanh, overflow-safe: e = exp(-2|x|) in (0,1]
    float ax = fabsf(acc);
    float e = __expf(-2.0f * ax);
    float th = (1.0f - e) / (1.0f + e);
    th = copysignf(th, acc);

    h = (m != 0) ? th : h;

    xp[(size_t)t * HH + j] = h;    // ys output (in-place)
    hs[(t + 1) & 1][j] = h;        // publish h for next step
    __syncthreads();
  }
}

extern "C" void kernel_launch(void* const* d_in, const int* in_sizes, int n_in,
                              void* d_out, int out_size, void* d_ws,
                              size_t ws_size, hipStream_t stream) {
  const int* tokens = (const int*)d_in[0];
  const float* emb = (const float*)d_in[1];
  const float* Wx0 = (const float*)d_in[2];
  const float* Wh0 = (const float*)d_in[3];
  const float* b0 = (const float*)d_in[4];
  const float* Wx1 = (const float*)d_in[5];
  const float* Wh1 = (const float*)d_in[6];
  const float* b1 = (const float*)d_in[7];
  float* out = (float*)d_out;
  float* ws = (float*)d_ws;  // 32 MB: xp0 -> ys0 (in-place)

  const int rows = BB * TT;            // 65536
  const int proj_blocks = rows / 64;   // 1024

  // Layer 0: xp0 = emb[tokens] @ Wx0 + b0   -> ws
  proj_kernel<true><<<proj_blocks, 256, 0, stream>>>(emb, tokens, Wx0, b0, ws);
  // Layer 0 recurrence (in-place: ws becomes ys0)
  rnn_kernel<<<BB, 128, 0, stream>>>(ws, Wh0, tokens);
  // Layer 1: xp1 = ys0 @ Wx1 + b1 -> out
  proj_kernel<false><<<proj_blocks, 256, 0, stream>>>(ws, nullptr, Wx1, b1, out);
  // Layer 1 recurrence (in-place: out becomes final ys1)
  rnn_kernel<<<BB, 128, 0, stream>>>(out, Wh1, tokens);
}